// Round 10
// baseline (195.764 us; speedup 1.0000x reference)
//
#include <hip/hip_runtime.h>

// DeformConv3D forward. B=2, C=Cout=64, D=8, H=56, W=56, K=27,
// stride=pad=dil=1, dg=1, groups=1.
// R10 = R8 (passing) + one change: per tap, ALL 32 corner loads issue into
//       registers before any interp consumes them (4x memory-level
//       parallelism per wave vs R8's per-group interleave). Layouts, LDS
//       geometry staging, pack, epilogue identical to R8.
#define CIN  64
#define COUT 64
#define DD   8
#define HH   56
#define WWID 56
#define KK   27
#define PP   (DD * HH * WWID)   // 25088
#define BB   2
#define NBLK 392                // PP/64 voxel tiles per batch
#define NSEG 3                  // tap segments (9 taps each)

typedef float    f32x4 __attribute__((ext_vector_type(4)));
typedef _Float16 h2    __attribute__((ext_vector_type(2)));
typedef _Float16 f16x8 __attribute__((ext_vector_type(8)));

__device__ __forceinline__ unsigned du(float f) {   // duplicate fp16 pair
    _Float16 h = (_Float16)f;
    unsigned short b = __builtin_bit_cast(unsigned short, h);
    return (unsigned)b * 0x10001u;
}
__device__ __forceinline__ h2 bch2(unsigned u) { return __builtin_bit_cast(h2, u); }

// prep grid ranges
#define G_ZERO 3136   // out_size/(256*4) float4 zero
#define G_TX   784    // BB*NBLK transpose tiles
#define G_PACK 432    // KK*2*4*64*8/256 weight pack

// ---------- fused prep: zero-out + x transpose->fp16 + w pack->fp16 ----------
__global__ __launch_bounds__(256) void prep_kernel(
    const float* __restrict__ x, const float* __restrict__ w,
    unsigned short* __restrict__ xTh, unsigned short* __restrict__ wPackH,
    float* __restrict__ out)
{
    const int bidx = blockIdx.x;
    const int tid  = threadIdx.x;

    if (bidx < G_ZERO) {
        const int idx = bidx * 256 + tid;
        ((float4*)out)[idx] = make_float4(0.f, 0.f, 0.f, 0.f);
    } else if (bidx < G_ZERO + G_TX) {
        // x[b][c][p] -> xTh[b][p][c] fp16 (rows of 64 ch = 128 B)
        __shared__ float tile[64 * 65];
        const int t  = bidx - G_ZERO;
        const int b  = t / NBLK;
        const int p0 = (t % NBLK) * 64;
        const int lane = tid & 63;
        const int wave = tid >> 6;
#pragma unroll
        for (int pass = 0; pass < 16; ++pass) {
            const int c = pass * 4 + wave;
            tile[lane * 65 + c] = x[((size_t)b * CIN + c) * PP + p0 + lane];
        }
        __syncthreads();
#pragma unroll
        for (int pass = 0; pass < 8; ++pass) {
            const int row = pass * 8 + wave * 2 + (lane >> 5);
            const int j   = lane & 31;                 // channel pair
            const float a = tile[row * 65 + 2 * j];
            const float c = tile[row * 65 + 2 * j + 1];
            const unsigned ua = (unsigned)__builtin_bit_cast(unsigned short, (_Float16)a);
            const unsigned uc = (unsigned)__builtin_bit_cast(unsigned short, (_Float16)c);
            ((unsigned*)xTh)[((size_t)b * PP + p0 + row) * 32 + j] = ua | (uc << 16);
        }
    } else {
        // wPackH[tap][kk][ct][lane][j] = B[k=kk*32+(lane>>4)*8+j][co=ct*16+(lane&15)]
        const int idx = (bidx - (G_ZERO + G_TX)) * 256 + tid;
        const int j    = idx & 7;
        const int lane = (idx >> 3) & 63;
        const int ct   = (idx >> 9) & 3;
        const int kk   = (idx >> 11) & 1;
        const int tap  = idx >> 12;
        const int c  = kk * 32 + (lane >> 4) * 8 + j;
        const int co = ct * 16 + (lane & 15);
        const _Float16 h = (_Float16)w[(co * CIN + c) * KK + tap];
        wPackH[idx] = __builtin_bit_cast(unsigned short, h);
    }
}

// ---------- fused main: fp16 datapath, pipelined geometry ----------
__global__ __launch_bounds__(256) void deform_mfma_kernel(
    const unsigned short* __restrict__ xTh, const float* __restrict__ off,
    const unsigned short* __restrict__ wPackH, float* __restrict__ out)
{
    // arena: cols 9216 | gOff 4096 | gWt 4096  = 17408 B; epilogue outb 16640 B
    __shared__ __align__(16) char smem[17408];
    unsigned short* colsH = (unsigned short*)smem;      // [64][72] fp16
    int4*  gOff = (int4*)(smem + 9216);   // [stage][wave][vox][2]
    uint4* gWt  = (uint4*)(smem + 13312); // [stage][wave][vox][2]
    float* outb = (float*)smem;           // [co][65] epilogue overlay

    const int tid  = threadIdx.x;
    const int wave = tid >> 6;
    const int lane = tid & 63;
    const int bid  = blockIdx.x;
    // grid 2352 = 8 XCDs x (98 tiles x 3 segs); same tile -> same XCD.
    const int xcd  = bid & 7;
    const int idx  = bid >> 3;
    const int tile = xcd * 98 + (idx % 98);
    const int seg  = idx / 98;
    const int tap0 = seg * 9;
    const int b    = tile / NBLK;
    const int p0   = (tile - b * NBLK) * 64;

    const char*  __restrict__ xc   = (const char*)(xTh + (size_t)b * PP * 64);
    const float* __restrict__ offb = off + (size_t)b * (3 * KK * PP);

    const int gl = lane & 15;
    const int pv = p0 + wave * 16 + gl;
    const int wq = pv % WWID;
    const int hq = (pv / WWID) % HH;
    const int dq = pv / (HH * WWID);
    const bool geo = (lane < 16);

    const int cq   = lane & 15;   // channel-quad (gather) / co col (consume)
    const int vsub = lane >> 4;   // voxel-sub (gather) / vox quad (consume)
    const int cb   = cq * 8;      // byte offset within a 128 B fp16 row

    f32x4 acc[4];
#pragma unroll
    for (int ct = 0; ct < 4; ++ct) acc[ct] = (f32x4){0.f, 0.f, 0.f, 0.f};

    // geometry for one tap into LDS stage s (lanes 0..15 of each wave)
    auto do_geo = [&](int tap, int s) {
        const int kd = tap / 9, kh = (tap / 3) % 3, kw = tap % 3;
        const float od = offb[(tap * 3 + 0) * PP + pv];
        const float oh = offb[(tap * 3 + 1) * PP + pv];
        const float ow = offb[(tap * 3 + 2) * PP + pv];
        const float pd = od + (float)(dq - 1 + kd);
        const float ph = oh + (float)(hq - 1 + kh);
        const float pw = ow + (float)(wq - 1 + kw);
        const float d0f = floorf(pd), h0f = floorf(ph), w0f = floorf(pw);
        const float fd = pd - d0f, fh = ph - h0f, fw = pw - w0f;
        const int d0 = (int)d0f, h0 = (int)h0f, w0 = (int)w0f;
        const int d1 = d0 + 1, h1 = h0 + 1, w1 = w0 + 1;

        const float wd0 = (1.f - fd) * ((d0 >= 0 && d0 < DD) ? 1.f : 0.f);
        const float wd1 = fd        * ((d1 >= 0 && d1 < DD) ? 1.f : 0.f);
        const float wh0 = (1.f - fh) * ((h0 >= 0 && h0 < HH) ? 1.f : 0.f);
        const float wh1 = fh        * ((h1 >= 0 && h1 < HH) ? 1.f : 0.f);
        const float ww0 = (1.f - fw) * ((w0 >= 0 && w0 < WWID) ? 1.f : 0.f);
        const float ww1 = fw        * ((w1 >= 0 && w1 < WWID) ? 1.f : 0.f);

        const int cd0 = min(max(d0, 0), DD - 1),   cd1 = min(max(d1, 0), DD - 1);
        const int ch0 = min(max(h0, 0), HH - 1),   ch1 = min(max(h1, 0), HH - 1);
        const int cw0 = min(max(w0, 0), WWID - 1), cw1 = min(max(w1, 0), WWID - 1);

        const int r00 = (cd0 * HH + ch0) * WWID;
        const int r01 = (cd0 * HH + ch1) * WWID;
        const int r10 = (cd1 * HH + ch0) * WWID;
        const int r11 = (cd1 * HH + ch1) * WWID;

        const int gi = ((s * 4 + wave) * 16 + gl) * 2;   // fp16 rows: <<7
        gOff[gi + 0] = make_int4((r00 + cw0) << 7, (r00 + cw1) << 7,
                                 (r01 + cw0) << 7, (r01 + cw1) << 7);
        gOff[gi + 1] = make_int4((r10 + cw0) << 7, (r10 + cw1) << 7,
                                 (r11 + cw0) << 7, (r11 + cw1) << 7);
        gWt[gi + 0] = make_uint4(du(wd0 * wh0 * ww0), du(wd0 * wh0 * ww1),
                                 du(wd0 * wh1 * ww0), du(wd0 * wh1 * ww1));
        gWt[gi + 1] = make_uint4(du(wd1 * wh0 * ww0), du(wd1 * wh0 * ww1),
                                 du(wd1 * wh1 * ww0), du(wd1 * wh1 * ww1));
    };

    if (geo) do_geo(tap0, tap0 & 1);

    for (int tap = tap0; tap < tap0 + 9; ++tap) {
        const int s = tap & 1;
        if (tap + 1 < tap0 + 9 && geo) do_geo(tap + 1, (tap + 1) & 1); // pipeline

        // ---- phase A: issue ALL 32 corner loads of this tap into registers ----
        uint2 R[4][8];
#pragma unroll
        for (int g = 0; g < 4; ++g) {
            const int v  = g * 4 + vsub;
            const int gi = ((s * 4 + wave) * 16 + v) * 2;
            const int4 o0 = gOff[gi + 0];
            const int4 o1 = gOff[gi + 1];
            R[g][0] = *(const uint2*)(xc + (o0.x + cb));
            R[g][1] = *(const uint2*)(xc + (o0.y + cb));
            R[g][2] = *(const uint2*)(xc + (o0.z + cb));
            R[g][3] = *(const uint2*)(xc + (o0.w + cb));
            R[g][4] = *(const uint2*)(xc + (o1.x + cb));
            R[g][5] = *(const uint2*)(xc + (o1.y + cb));
            R[g][6] = *(const uint2*)(xc + (o1.z + cb));
            R[g][7] = *(const uint2*)(xc + (o1.w + cb));
        }

        // ---- phase B: interp + cols write (consumes R) ----
#pragma unroll
        for (int g = 0; g < 4; ++g) {
            const int v  = g * 4 + vsub;
            const int gi = ((s * 4 + wave) * 16 + v) * 2;
            const uint4 w0 = gWt[gi + 0];
            const uint4 w1 = gWt[gi + 1];

            h2 A01 = (h2)0, A23 = (h2)0;
            { const h2 wv = bch2(w0.x); A01 += bch2(R[g][0].x) * wv; A23 += bch2(R[g][0].y) * wv; }
            { const h2 wv = bch2(w0.y); A01 += bch2(R[g][1].x) * wv; A23 += bch2(R[g][1].y) * wv; }
            { const h2 wv = bch2(w0.z); A01 += bch2(R[g][2].x) * wv; A23 += bch2(R[g][2].y) * wv; }
            { const h2 wv = bch2(w0.w); A01 += bch2(R[g][3].x) * wv; A23 += bch2(R[g][3].y) * wv; }
            { const h2 wv = bch2(w1.x); A01 += bch2(R[g][4].x) * wv; A23 += bch2(R[g][4].y) * wv; }
            { const h2 wv = bch2(w1.y); A01 += bch2(R[g][5].x) * wv; A23 += bch2(R[g][5].y) * wv; }
            { const h2 wv = bch2(w1.z); A01 += bch2(R[g][6].x) * wv; A23 += bch2(R[g][6].y) * wv; }
            { const h2 wv = bch2(w1.w); A01 += bch2(R[g][7].x) * wv; A23 += bch2(R[g][7].y) * wv; }

            uint2 pk;
            pk.x = __builtin_bit_cast(unsigned, A01);
            pk.y = __builtin_bit_cast(unsigned, A23);
            *(uint2*)(colsH + (wave * 16 + v) * 72 + cq * 4) = pk;
        }

        // ---- consume: wave w: vox band [16w,16w+16) x all 64 co ----
#pragma unroll
        for (int kk = 0; kk < 2; ++kk) {
            const f16x8 afrag = *(const f16x8*)
                (colsH + (wave * 16 + cq) * 72 + kk * 32 + vsub * 8);
            const f16x8* wp = (const f16x8*)
                (wPackH + (size_t)(tap * 2 + kk) * 4 * 64 * 8);
#pragma unroll
            for (int ct = 0; ct < 4; ++ct) {
                const f16x8 bfrag = wp[ct * 64 + lane];
                acc[ct] = __builtin_amdgcn_mfma_f32_16x16x32_f16(
                    afrag, bfrag, acc[ct], 0, 0, 0);
            }
        }
    }

    // ---- epilogue: C layout col=lane&15 (co), row=(lane>>4)*4+reg (vox) ----
    __syncthreads();
#pragma unroll
    for (int ct = 0; ct < 4; ++ct) {
#pragma unroll
        for (int reg = 0; reg < 4; ++reg) {
            const int vox = wave * 16 + vsub * 4 + reg;
            const int co  = ct * 16 + cq;
            outb[co * 65 + vox] = acc[ct][reg];
        }
    }
    __syncthreads();

#pragma unroll
    for (int i = 0; i < 16; ++i) {
        const int co = wave * 16 + i;
        atomicAdd(&out[((size_t)b * COUT + co) * PP + p0 + lane],
                  outb[co * 65 + lane]);
    }
}

// ---------- fallback (ws-free, R1 structure) ----------
__global__ __launch_bounds__(128) void deform_fallback_kernel(
    const float* __restrict__ x, const float* __restrict__ off,
    const float* __restrict__ w, float* __restrict__ out)
{
    const int co_half = blockIdx.x / 392;
    const int vox     = (blockIdx.x % 392) * 128 + threadIdx.x;
    const int b  = vox / PP;
    const int p  = vox - b * PP;
    const int wq = p % WWID;
    const int hq = (p / WWID) % HH;
    const int dq = p / (HH * WWID);
    const int co_base = co_half * 32;
    const float* xb   = x + (size_t)b * (CIN * PP);
    const float* offb = off + (size_t)b * (3 * KK * PP) + p;
    float acc[32];
#pragma unroll
    for (int j = 0; j < 32; ++j) acc[j] = 0.f;
    for (int k = 0; k < KK; ++k) {
        const int kd = k / 9, kh = (k / 3) % 3, kw = k % 3;
        const float od = offb[(k * 3 + 0) * PP];
        const float oh = offb[(k * 3 + 1) * PP];
        const float ow = offb[(k * 3 + 2) * PP];
        const float pd = od + (float)(dq - 1 + kd);
        const float ph = oh + (float)(hq - 1 + kh);
        const float pw = ow + (float)(wq - 1 + kw);
        const float d0f = floorf(pd), h0f = floorf(ph), w0f = floorf(pw);
        const float fd = pd - d0f, fh = ph - h0f, fw = pw - w0f;
        const int d0 = (int)d0f, h0 = (int)h0f, w0 = (int)w0f;
        const int d1 = d0 + 1, h1 = h0 + 1, w1 = w0 + 1;
        const float wd0 = (1.f - fd) * ((d0 >= 0 && d0 < DD) ? 1.f : 0.f);
        const float wd1 = fd        * ((d1 >= 0 && d1 < DD) ? 1.f : 0.f);
        const float wh0 = (1.f - fh) * ((h0 >= 0 && h0 < HH) ? 1.f : 0.f);
        const float wh1 = fh        * ((h1 >= 0 && h1 < HH) ? 1.f : 0.f);
        const float ww0 = (1.f - fw) * ((w0 >= 0 && w0 < WWID) ? 1.f : 0.f);
        const float ww1 = fw        * ((w1 >= 0 && w1 < WWID) ? 1.f : 0.f);
        const int cd0 = min(max(d0, 0), DD - 1),   cd1 = min(max(d1, 0), DD - 1);
        const int ch0 = min(max(h0, 0), HH - 1),   ch1 = min(max(h1, 0), HH - 1);
        const int cw0 = min(max(w0, 0), WWID - 1), cw1 = min(max(w1, 0), WWID - 1);
        const int l000 = (cd0 * HH + ch0) * WWID + cw0;
        const int l001 = (cd0 * HH + ch0) * WWID + cw1;
        const int l010 = (cd0 * HH + ch1) * WWID + cw0;
        const int l011 = (cd0 * HH + ch1) * WWID + cw1;
        const int l100 = (cd1 * HH + ch0) * WWID + cw0;
        const int l101 = (cd1 * HH + ch0) * WWID + cw1;
        const int l110 = (cd1 * HH + ch1) * WWID + cw0;
        const int l111 = (cd1 * HH + ch1) * WWID + cw1;
        const float c000 = wd0 * wh0 * ww0, c001 = wd0 * wh0 * ww1;
        const float c010 = wd0 * wh1 * ww0, c011 = wd0 * wh1 * ww1;
        const float c100 = wd1 * wh0 * ww0, c101 = wd1 * wh0 * ww1;
        const float c110 = wd1 * wh1 * ww0, c111 = wd1 * wh1 * ww1;
        for (int c = 0; c < CIN; ++c) {
            const float* xcp = xb + (size_t)c * PP;
            float v = c000 * xcp[l000] + c001 * xcp[l001]
                    + c010 * xcp[l010] + c011 * xcp[l011]
                    + c100 * xcp[l100] + c101 * xcp[l101]
                    + c110 * xcp[l110] + c111 * xcp[l111];
#pragma unroll
            for (int j = 0; j < 32; ++j)
                acc[j] += w[((size_t)(co_base + j) * CIN + c) * KK + k] * v;
        }
    }
    float* ob = out + (size_t)b * (COUT * PP) + (size_t)co_base * PP + p;
#pragma unroll
    for (int j = 0; j < 32; ++j) ob[j * PP] = acc[j];
}

extern "C" void kernel_launch(void* const* d_in, const int* in_sizes, int n_in,
                              void* d_out, int out_size, void* d_ws, size_t ws_size,
                              hipStream_t stream)
{
    const float* x   = (const float*)d_in[0];
    const float* off = (const float*)d_in[1];
    const float* w   = (const float*)d_in[2];
    float* out = (float*)d_out;

    const size_t xt_bytes = (size_t)BB * PP * CIN * 2;        // 6,422,528 (fp16)
    const size_t wp_bytes = (size_t)KK * 2 * 4 * 64 * 8 * 2;  //   221,184 (fp16)
    const size_t need = xt_bytes + wp_bytes;

    if (ws_size >= need) {
        unsigned short* xTh    = (unsigned short*)d_ws;
        unsigned short* wPackH = (unsigned short*)((char*)d_ws + xt_bytes);
        prep_kernel<<<G_ZERO + G_TX + G_PACK, 256, 0, stream>>>(
            x, w, xTh, wPackH, out);
        deform_mfma_kernel<<<8 * 98 * NSEG, 256, 0, stream>>>(
            xTh, off, wPackH, out);
    } else {
        deform_fallback_kernel<<<2 * 392, 128, 0, stream>>>(x, off, w, out);
    }
}

// Round 11
// 158.465 us; speedup vs baseline: 1.2354x; 1.2354x over previous
//
#include <hip/hip_runtime.h>

// DeformConv3D forward. B=2, C=Cout=64, D=8, H=56, W=56, K=27,
// stride=pad=dil=1, dg=1, groups=1.
// R11 = R8 (passing, 192us) + one change: gather lane map is now
//       (8 vox x 8 ch-octets, dwordx4 16B/lane) instead of
//       (4 vox x 16 ch-quads, dwordx2 8B/lane) -> 16 gather insts/tap
//       instead of 32 (address-processing bound). Geometry staging, cols
//       layout, MFMA consume, epilogue identical to R8.
#define CIN  64
#define COUT 64
#define DD   8
#define HH   56
#define WWID 56
#define KK   27
#define PP   (DD * HH * WWID)   // 25088
#define BB   2
#define NBLK 392                // PP/64 voxel tiles per batch
#define NSEG 3                  // tap segments (9 taps each)

typedef float    f32x4 __attribute__((ext_vector_type(4)));
typedef _Float16 h2    __attribute__((ext_vector_type(2)));
typedef _Float16 f16x8 __attribute__((ext_vector_type(8)));

__device__ __forceinline__ unsigned du(float f) {   // duplicate fp16 pair
    _Float16 h = (_Float16)f;
    unsigned short b = __builtin_bit_cast(unsigned short, h);
    return (unsigned)b * 0x10001u;
}
__device__ __forceinline__ h2 bch2(unsigned u) { return __builtin_bit_cast(h2, u); }
__device__ __forceinline__ unsigned bcu(h2 v) { return __builtin_bit_cast(unsigned, v); }

// prep grid ranges
#define G_ZERO 3136   // out_size/(256*4) float4 zero
#define G_TX   784    // BB*NBLK transpose tiles
#define G_PACK 432    // KK*2*4*64*8/256 weight pack

// ---------- fused prep: zero-out + x transpose->fp16 + w pack->fp16 ----------
__global__ __launch_bounds__(256) void prep_kernel(
    const float* __restrict__ x, const float* __restrict__ w,
    unsigned short* __restrict__ xTh, unsigned short* __restrict__ wPackH,
    float* __restrict__ out)
{
    const int bidx = blockIdx.x;
    const int tid  = threadIdx.x;

    if (bidx < G_ZERO) {
        const int idx = bidx * 256 + tid;
        ((float4*)out)[idx] = make_float4(0.f, 0.f, 0.f, 0.f);
    } else if (bidx < G_ZERO + G_TX) {
        // x[b][c][p] -> xTh[b][p][c] fp16 (rows of 64 ch = 128 B)
        __shared__ float tile[64 * 65];
        const int t  = bidx - G_ZERO;
        const int b  = t / NBLK;
        const int p0 = (t % NBLK) * 64;
        const int lane = tid & 63;
        const int wave = tid >> 6;
#pragma unroll
        for (int pass = 0; pass < 16; ++pass) {
            const int c = pass * 4 + wave;
            tile[lane * 65 + c] = x[((size_t)b * CIN + c) * PP + p0 + lane];
        }
        __syncthreads();
#pragma unroll
        for (int pass = 0; pass < 8; ++pass) {
            const int row = pass * 8 + wave * 2 + (lane >> 5);
            const int j   = lane & 31;                 // channel pair
            const float a = tile[row * 65 + 2 * j];
            const float c = tile[row * 65 + 2 * j + 1];
            const unsigned ua = (unsigned)__builtin_bit_cast(unsigned short, (_Float16)a);
            const unsigned uc = (unsigned)__builtin_bit_cast(unsigned short, (_Float16)c);
            ((unsigned*)xTh)[((size_t)b * PP + p0 + row) * 32 + j] = ua | (uc << 16);
        }
    } else {
        // wPackH[tap][kk][ct][lane][j] = B[k=kk*32+(lane>>4)*8+j][co=ct*16+(lane&15)]
        const int idx = (bidx - (G_ZERO + G_TX)) * 256 + tid;
        const int j    = idx & 7;
        const int lane = (idx >> 3) & 63;
        const int ct   = (idx >> 9) & 3;
        const int kk   = (idx >> 11) & 1;
        const int tap  = idx >> 12;
        const int c  = kk * 32 + (lane >> 4) * 8 + j;
        const int co = ct * 16 + (lane & 15);
        const _Float16 h = (_Float16)w[(co * CIN + c) * KK + tap];
        wPackH[idx] = __builtin_bit_cast(unsigned short, h);
    }
}

// ---------- fused main: fp16 datapath, pipelined geometry ----------
__global__ __launch_bounds__(256) void deform_mfma_kernel(
    const unsigned short* __restrict__ xTh, const float* __restrict__ off,
    const unsigned short* __restrict__ wPackH, float* __restrict__ out)
{
    // arena: cols 9216 | gOff 4096 | gWt 4096  = 17408 B; epilogue outb 16640 B
    __shared__ __align__(16) char smem[17408];
    unsigned short* colsH = (unsigned short*)smem;      // [64][72] fp16
    int4*  gOff = (int4*)(smem + 9216);   // [stage][wave][vox][2]
    uint4* gWt  = (uint4*)(smem + 13312); // [stage][wave][vox][2]
    float* outb = (float*)smem;           // [co][65] epilogue overlay

    const int tid  = threadIdx.x;
    const int wave = tid >> 6;
    const int lane = tid & 63;
    const int bid  = blockIdx.x;
    // grid 2352 = 8 XCDs x (98 tiles x 3 segs); same tile -> same XCD.
    const int xcd  = bid & 7;
    const int idx  = bid >> 3;
    const int tile = xcd * 98 + (idx % 98);
    const int seg  = idx / 98;
    const int tap0 = seg * 9;
    const int b    = tile / NBLK;
    const int p0   = (tile - b * NBLK) * 64;

    const char*  __restrict__ xc   = (const char*)(xTh + (size_t)b * PP * 64);
    const float* __restrict__ offb = off + (size_t)b * (3 * KK * PP);

    const int gl = lane & 15;
    const int pv = p0 + wave * 16 + gl;
    const int wq = pv % WWID;
    const int hq = (pv / WWID) % HH;
    const int dq = pv / (HH * WWID);
    const bool geo = (lane < 16);

    const int cq   = lane & 15;   // co col / afrag vox (consume)
    const int vsub = lane >> 4;   // vox quad (consume/epilogue)
    const int v8   = lane >> 3;   // voxel-in-half (gather)
    const int oct  = lane & 7;    // channel octet (gather)
    const int ob8  = oct * 16;    // byte offset of octet within 128 B row

    f32x4 acc[4];
#pragma unroll
    for (int ct = 0; ct < 4; ++ct) acc[ct] = (f32x4){0.f, 0.f, 0.f, 0.f};

    // geometry for one tap into LDS stage s (lanes 0..15 of each wave)
    auto do_geo = [&](int tap, int s) {
        const int kd = tap / 9, kh = (tap / 3) % 3, kw = tap % 3;
        const float od = offb[(tap * 3 + 0) * PP + pv];
        const float oh = offb[(tap * 3 + 1) * PP + pv];
        const float ow = offb[(tap * 3 + 2) * PP + pv];
        const float pd = od + (float)(dq - 1 + kd);
        const float ph = oh + (float)(hq - 1 + kh);
        const float pw = ow + (float)(wq - 1 + kw);
        const float d0f = floorf(pd), h0f = floorf(ph), w0f = floorf(pw);
        const float fd = pd - d0f, fh = ph - h0f, fw = pw - w0f;
        const int d0 = (int)d0f, h0 = (int)h0f, w0 = (int)w0f;
        const int d1 = d0 + 1, h1 = h0 + 1, w1 = w0 + 1;

        const float wd0 = (1.f - fd) * ((d0 >= 0 && d0 < DD) ? 1.f : 0.f);
        const float wd1 = fd        * ((d1 >= 0 && d1 < DD) ? 1.f : 0.f);
        const float wh0 = (1.f - fh) * ((h0 >= 0 && h0 < HH) ? 1.f : 0.f);
        const float wh1 = fh        * ((h1 >= 0 && h1 < HH) ? 1.f : 0.f);
        const float ww0 = (1.f - fw) * ((w0 >= 0 && w0 < WWID) ? 1.f : 0.f);
        const float ww1 = fw        * ((w1 >= 0 && w1 < WWID) ? 1.f : 0.f);

        const int cd0 = min(max(d0, 0), DD - 1),   cd1 = min(max(d1, 0), DD - 1);
        const int ch0 = min(max(h0, 0), HH - 1),   ch1 = min(max(h1, 0), HH - 1);
        const int cw0 = min(max(w0, 0), WWID - 1), cw1 = min(max(w1, 0), WWID - 1);

        const int r00 = (cd0 * HH + ch0) * WWID;
        const int r01 = (cd0 * HH + ch1) * WWID;
        const int r10 = (cd1 * HH + ch0) * WWID;
        const int r11 = (cd1 * HH + ch1) * WWID;

        const int gi = ((s * 4 + wave) * 16 + gl) * 2;   // fp16 rows: <<7
        gOff[gi + 0] = make_int4((r00 + cw0) << 7, (r00 + cw1) << 7,
                                 (r01 + cw0) << 7, (r01 + cw1) << 7);
        gOff[gi + 1] = make_int4((r10 + cw0) << 7, (r10 + cw1) << 7,
                                 (r11 + cw0) << 7, (r11 + cw1) << 7);
        gWt[gi + 0] = make_uint4(du(wd0 * wh0 * ww0), du(wd0 * wh0 * ww1),
                                 du(wd0 * wh1 * ww0), du(wd0 * wh1 * ww1));
        gWt[gi + 1] = make_uint4(du(wd1 * wh0 * ww0), du(wd1 * wh0 * ww1),
                                 du(wd1 * wh1 * ww0), du(wd1 * wh1 * ww1));
    };

    if (geo) do_geo(tap0, tap0 & 1);

    for (int tap = tap0; tap < tap0 + 9; ++tap) {
        const int s = tap & 1;
        if (tap + 1 < tap0 + 9 && geo) do_geo(tap + 1, (tap + 1) & 1); // pipeline

        // ---- gather: lane = (v8, oct); 2 halves cover the 16 voxels.
        //      8 dwordx4 corner loads per half (16 insts/tap vs R8's 32). ----
#pragma unroll
        for (int half = 0; half < 2; ++half) {
            const int v  = half * 8 + v8;
            const int gi = ((s * 4 + wave) * 16 + v) * 2;
            const int4 o0 = gOff[gi + 0];
            const int4 o1 = gOff[gi + 1];

            const uint4 r0 = *(const uint4*)(xc + (o0.x + ob8));
            const uint4 r1 = *(const uint4*)(xc + (o0.y + ob8));
            const uint4 r2 = *(const uint4*)(xc + (o0.z + ob8));
            const uint4 r3 = *(const uint4*)(xc + (o0.w + ob8));
            const uint4 r4 = *(const uint4*)(xc + (o1.x + ob8));
            const uint4 r5 = *(const uint4*)(xc + (o1.y + ob8));
            const uint4 r6 = *(const uint4*)(xc + (o1.z + ob8));
            const uint4 r7 = *(const uint4*)(xc + (o1.w + ob8));

            const uint4 w0 = gWt[gi + 0];
            const uint4 w1 = gWt[gi + 1];

            h2 A01 = (h2)0, A23 = (h2)0, A45 = (h2)0, A67 = (h2)0;
            { const h2 wv = bch2(w0.x); A01 += bch2(r0.x) * wv; A23 += bch2(r0.y) * wv;
                                        A45 += bch2(r0.z) * wv; A67 += bch2(r0.w) * wv; }
            { const h2 wv = bch2(w0.y); A01 += bch2(r1.x) * wv; A23 += bch2(r1.y) * wv;
                                        A45 += bch2(r1.z) * wv; A67 += bch2(r1.w) * wv; }
            { const h2 wv = bch2(w0.z); A01 += bch2(r2.x) * wv; A23 += bch2(r2.y) * wv;
                                        A45 += bch2(r2.z) * wv; A67 += bch2(r2.w) * wv; }
            { const h2 wv = bch2(w0.w); A01 += bch2(r3.x) * wv; A23 += bch2(r3.y) * wv;
                                        A45 += bch2(r3.z) * wv; A67 += bch2(r3.w) * wv; }
            { const h2 wv = bch2(w1.x); A01 += bch2(r4.x) * wv; A23 += bch2(r4.y) * wv;
                                        A45 += bch2(r4.z) * wv; A67 += bch2(r4.w) * wv; }
            { const h2 wv = bch2(w1.y); A01 += bch2(r5.x) * wv; A23 += bch2(r5.y) * wv;
                                        A45 += bch2(r5.z) * wv; A67 += bch2(r5.w) * wv; }
            { const h2 wv = bch2(w1.z); A01 += bch2(r6.x) * wv; A23 += bch2(r6.y) * wv;
                                        A45 += bch2(r6.z) * wv; A67 += bch2(r6.w) * wv; }
            { const h2 wv = bch2(w1.w); A01 += bch2(r7.x) * wv; A23 += bch2(r7.y) * wv;
                                        A45 += bch2(r7.z) * wv; A67 += bch2(r7.w) * wv; }

            uint4 pk;
            pk.x = bcu(A01); pk.y = bcu(A23); pk.z = bcu(A45); pk.w = bcu(A67);
            // byte addr = (wave*16+v)*144 + oct*16 : 16B-aligned, wave-private
            *(uint4*)(colsH + (wave * 16 + v) * 72 + oct * 8) = pk;
        }

        // ---- consume: wave w: vox band [16w,16w+16) x all 64 co ----
#pragma unroll
        for (int kk = 0; kk < 2; ++kk) {
            const f16x8 afrag = *(const f16x8*)
                (colsH + (wave * 16 + cq) * 72 + kk * 32 + vsub * 8);
            const f16x8* wp = (const f16x8*)
                (wPackH + (size_t)(tap * 2 + kk) * 4 * 64 * 8);
#pragma unroll
            for (int ct = 0; ct < 4; ++ct) {
                const f16x8 bfrag = wp[ct * 64 + lane];
                acc[ct] = __builtin_amdgcn_mfma_f32_16x16x32_f16(
                    afrag, bfrag, acc[ct], 0, 0, 0);
            }
        }
    }

    // ---- epilogue: C layout col=lane&15 (co), row=(lane>>4)*4+reg (vox) ----
    __syncthreads();
#pragma unroll
    for (int ct = 0; ct < 4; ++ct) {
#pragma unroll
        for (int reg = 0; reg < 4; ++reg) {
            const int vox = wave * 16 + vsub * 4 + reg;
            const int co  = ct * 16 + cq;
            outb[co * 65 + vox] = acc[ct][reg];
        }
    }
    __syncthreads();

#pragma unroll
    for (int i = 0; i < 16; ++i) {
        const int co = wave * 16 + i;
        atomicAdd(&out[((size_t)b * COUT + co) * PP + p0 + lane],
                  outb[co * 65 + lane]);
    }
}

// ---------- fallback (ws-free, R1 structure) ----------
__global__ __launch_bounds__(128) void deform_fallback_kernel(
    const float* __restrict__ x, const float* __restrict__ off,
    const float* __restrict__ w, float* __restrict__ out)
{
    const int co_half = blockIdx.x / 392;
    const int vox     = (blockIdx.x % 392) * 128 + threadIdx.x;
    const int b  = vox / PP;
    const int p  = vox - b * PP;
    const int wq = p % WWID;
    const int hq = (p / WWID) % HH;
    const int dq = p / (HH * WWID);
    const int co_base = co_half * 32;
    const float* xb   = x + (size_t)b * (CIN * PP);
    const float* offb = off + (size_t)b * (3 * KK * PP) + p;
    float acc[32];
#pragma unroll
    for (int j = 0; j < 32; ++j) acc[j] = 0.f;
    for (int k = 0; k < KK; ++k) {
        const int kd = k / 9, kh = (k / 3) % 3, kw = k % 3;
        const float od = offb[(k * 3 + 0) * PP];
        const float oh = offb[(k * 3 + 1) * PP];
        const float ow = offb[(k * 3 + 2) * PP];
        const float pd = od + (float)(dq - 1 + kd);
        const float ph = oh + (float)(hq - 1 + kh);
        const float pw = ow + (float)(wq - 1 + kw);
        const float d0f = floorf(pd), h0f = floorf(ph), w0f = floorf(pw);
        const float fd = pd - d0f, fh = ph - h0f, fw = pw - w0f;
        const int d0 = (int)d0f, h0 = (int)h0f, w0 = (int)w0f;
        const int d1 = d0 + 1, h1 = h0 + 1, w1 = w0 + 1;
        const float wd0 = (1.f - fd) * ((d0 >= 0 && d0 < DD) ? 1.f : 0.f);
        const float wd1 = fd        * ((d1 >= 0 && d1 < DD) ? 1.f : 0.f);
        const float wh0 = (1.f - fh) * ((h0 >= 0 && h0 < HH) ? 1.f : 0.f);
        const float wh1 = fh        * ((h1 >= 0 && h1 < HH) ? 1.f : 0.f);
        const float ww0 = (1.f - fw) * ((w0 >= 0 && w0 < WWID) ? 1.f : 0.f);
        const float ww1 = fw        * ((w1 >= 0 && w1 < WWID) ? 1.f : 0.f);
        const int cd0 = min(max(d0, 0), DD - 1),   cd1 = min(max(d1, 0), DD - 1);
        const int ch0 = min(max(h0, 0), HH - 1),   ch1 = min(max(h1, 0), HH - 1);
        const int cw0 = min(max(w0, 0), WWID - 1), cw1 = min(max(w1, 0), WWID - 1);
        const int l000 = (cd0 * HH + ch0) * WWID + cw0;
        const int l001 = (cd0 * HH + ch0) * WWID + cw1;
        const int l010 = (cd0 * HH + ch1) * WWID + cw0;
        const int l011 = (cd0 * HH + ch1) * WWID + cw1;
        const int l100 = (cd1 * HH + ch0) * WWID + cw0;
        const int l101 = (cd1 * HH + ch0) * WWID + cw1;
        const int l110 = (cd1 * HH + ch1) * WWID + cw0;
        const int l111 = (cd1 * HH + ch1) * WWID + cw1;
        const float c000 = wd0 * wh0 * ww0, c001 = wd0 * wh0 * ww1;
        const float c010 = wd0 * wh1 * ww0, c011 = wd0 * wh1 * ww1;
        const float c100 = wd1 * wh0 * ww0, c101 = wd1 * wh0 * ww1;
        const float c110 = wd1 * wh1 * ww0, c111 = wd1 * wh1 * ww1;
        for (int c = 0; c < CIN; ++c) {
            const float* xcp = xb + (size_t)c * PP;
            float v = c000 * xcp[l000] + c001 * xcp[l001]
                    + c010 * xcp[l010] + c011 * xcp[l011]
                    + c100 * xcp[l100] + c101 * xcp[l101]
                    + c110 * xcp[l110] + c111 * xcp[l111];
#pragma unroll
            for (int j = 0; j < 32; ++j)
                acc[j] += w[((size_t)(co_base + j) * CIN + c) * KK + k] * v;
        }
    }
    float* ob = out + (size_t)b * (COUT * PP) + (size_t)co_base * PP + p;
#pragma unroll
    for (int j = 0; j < 32; ++j) ob[j * PP] = acc[j];
}

extern "C" void kernel_launch(void* const* d_in, const int* in_sizes, int n_in,
                              void* d_out, int out_size, void* d_ws, size_t ws_size,
                              hipStream_t stream)
{
    const float* x   = (const float*)d_in[0];
    const float* off = (const float*)d_in[1];
    const float* w   = (const float*)d_in[2];
    float* out = (float*)d_out;

    const size_t xt_bytes = (size_t)BB * PP * CIN * 2;        // 6,422,528 (fp16)
    const size_t wp_bytes = (size_t)KK * 2 * 4 * 64 * 8 * 2;  //   221,184 (fp16)
    const size_t need = xt_bytes + wp_bytes;

    if (ws_size >= need) {
        unsigned short* xTh    = (unsigned short*)d_ws;
        unsigned short* wPackH = (unsigned short*)((char*)d_ws + xt_bytes);
        prep_kernel<<<G_ZERO + G_TX + G_PACK, 256, 0, stream>>>(
            x, w, xTh, wPackH, out);
        deform_mfma_kernel<<<8 * 98 * NSEG, 256, 0, stream>>>(
            xTh, off, wPackH, out);
    } else {
        deform_fallback_kernel<<<2 * 392, 128, 0, stream>>>(x, off, w, out);
    }
}